// Round 1
// baseline (622.271 us; speedup 1.0000x reference)
//
#include <hip/hip_runtime.h>

// ISNE gather + masked-mean.
// Inputs (setup_inputs order):
//   0: node_parameters [1e6, 128] f32
//   1: node_indices    [16384]    i32
//   2: pos_idx         [16384,32] i32
//   3: pos_len         [16384]    i32
//   4: neg_idx         [16384,32] i32
//   5: neg_len         [16384]    i32
// Output: concat(node_embeds, pos_embeds, neg_embeds) each [16384,128] f32.

constexpr int B = 16384;
constexpr int D = 128;
constexpr int K = 32;

// One block per batch row. 256 threads:
//   tid 0..127  -> pos list, tid 128..255 -> neg list (loads overlap).
//   Within a side: 4 k-groups x 32 lanes; each 32-lane group reads one full
//   512B embedding row as float4 (coalesced). Reduce 4 partials via
//   shfl_xor(32) + LDS.
__global__ __launch_bounds__(256) void isne_kernel(
    const float* __restrict__ table,
    const int*   __restrict__ node_idx,
    const int*   __restrict__ pos_idx,
    const int*   __restrict__ pos_len,
    const int*   __restrict__ neg_idx,
    const int*   __restrict__ neg_len,
    float*       __restrict__ out)
{
    const int b     = blockIdx.x;
    const int tid   = threadIdx.x;
    const int side  = tid >> 7;       // 0 = pos, 1 = neg
    const int stid  = tid & 127;
    const int grp   = stid >> 5;      // k-offset group 0..3
    const int lane4 = stid & 31;      // float4 index within the 128-float row
    const int sub   = stid >> 6;      // which wave within the side (0/1)

    const float4* t4   = reinterpret_cast<const float4*>(table);
    float4*       out4 = reinterpret_cast<float4*>(out);

    // Node embedding gather: 32 threads x float4 = 512B row copy.
    if (tid < 32) {
        const int ni = node_idx[b];
        out4[(size_t)b * 32 + tid] = t4[(size_t)ni * 32 + tid];
    }

    const int* idxp = side ? neg_idx : pos_idx;
    const int  len  = (side ? neg_len : pos_len)[b];

    float4 acc = make_float4(0.f, 0.f, 0.f, 0.f);
    for (int k = grp; k < len; k += 4) {
        const int r = idxp[b * K + k];
        const float4 v = t4[(size_t)r * 32 + lane4];
        acc.x += v.x; acc.y += v.y; acc.z += v.z; acc.w += v.w;
    }

    // Combine k-groups (g, g+1) held by the two halves of each 64-lane wave.
    acc.x += __shfl_xor(acc.x, 32);
    acc.y += __shfl_xor(acc.y, 32);
    acc.z += __shfl_xor(acc.z, 32);
    acc.w += __shfl_xor(acc.w, 32);

    // Cross-wave combine within each side via 1KB LDS.
    __shared__ float4 smem[2][32];
    if (sub == 1 && (stid & 63) < 32) smem[side][lane4] = acc;
    __syncthreads();
    if (sub == 0 && stid < 32) {
        float4 o = smem[side][lane4];
        o.x += acc.x; o.y += acc.y; o.z += acc.z; o.w += acc.w;
        const float inv = (len > 0) ? (1.0f / (float)len) : 0.0f;
        o.x *= inv; o.y *= inv; o.z *= inv; o.w *= inv;
        out4[((size_t)(1 + side) * B + b) * 32 + lane4] = o;
    }
}

extern "C" void kernel_launch(void* const* d_in, const int* in_sizes, int n_in,
                              void* d_out, int out_size, void* d_ws, size_t ws_size,
                              hipStream_t stream)
{
    const float* table    = (const float*)d_in[0];
    const int*   node_idx = (const int*)d_in[1];
    const int*   pos_idx  = (const int*)d_in[2];
    const int*   pos_len  = (const int*)d_in[3];
    const int*   neg_idx  = (const int*)d_in[4];
    const int*   neg_len  = (const int*)d_in[5];
    float*       out      = (float*)d_out;

    isne_kernel<<<B, 256, 0, stream>>>(table, node_idx, pos_idx, pos_len,
                                       neg_idx, neg_len, out);
}

// Round 2
// 611.865 us; speedup vs baseline: 1.0170x; 1.0170x over previous
//
#include <hip/hip_runtime.h>

// ISNE gather + masked-mean.
// Inputs (setup_inputs order):
//   0: node_parameters [1e6, 128] f32
//   1: node_indices    [16384]    i32
//   2: pos_idx         [16384,32] i32
//   3: pos_len         [16384]    i32
//   4: neg_idx         [16384,32] i32
//   5: neg_len         [16384]    i32
// Output: concat(node_embeds, pos_embeds, neg_embeds) each [16384,128] f32.

constexpr int B = 16384;
constexpr int K = 32;

// One block per batch row, 256 threads.
//   side = tid>>7 (0=pos, 1=neg); within a side, 4 groups x 32 lanes.
//   Group g covers contiguous k in [8g, 8g+8). Invalid k are clamped to
//   list position 0 (its row is loaded by group 0 anyway -> L2 hit, no extra
//   HBM traffic) and masked out of the accumulation. All 8 index loads and
//   all 8 row loads are unconditional and independent -> 8 wave-wide 1KB
//   loads in flight per wave, fully hiding HBM latency.
__global__ __launch_bounds__(256) void isne_kernel(
    const float* __restrict__ table,
    const int*   __restrict__ node_idx,
    const int*   __restrict__ pos_idx,
    const int*   __restrict__ pos_len,
    const int*   __restrict__ neg_idx,
    const int*   __restrict__ neg_len,
    float*       __restrict__ out)
{
    const int b     = blockIdx.x;
    const int tid   = threadIdx.x;
    const int side  = tid >> 7;       // 0 = pos, 1 = neg
    const int stid  = tid & 127;
    const int grp   = stid >> 5;      // group 0..3 -> k base = 8*grp
    const int lane4 = stid & 31;      // float4 chunk within the 128-float row
    const int sub   = stid >> 6;      // wave-within-side (0/1)
    const int kbase = grp * 8;

    const float4* t4   = reinterpret_cast<const float4*>(table);
    float4*       out4 = reinterpret_cast<float4*>(out);

    // Node embedding gather: 32 threads x float4 = one 512B row copy.
    if (tid < 32) {
        const int ni = node_idx[b];
        out4[(size_t)b * 32 + tid] = t4[(size_t)ni * 32 + tid];
    }

    const int* idxp = side ? neg_idx : pos_idx;
    const int  len  = (side ? neg_len : pos_len)[b];   // uniform -> s_load

    // 8 independent index loads (clamped), issued back-to-back.
    int ridx[8];
#pragma unroll
    for (int j = 0; j < 8; ++j) {
        const int k  = kbase + j;
        const int kk = (k < len) ? k : 0;
        ridx[j] = idxp[b * K + kk];
    }

    // 8 independent wave-wide row loads in flight.
    float4 v[8];
#pragma unroll
    for (int j = 0; j < 8; ++j) {
        v[j] = t4[(size_t)ridx[j] * 32 + lane4];
    }

    float4 acc = make_float4(0.f, 0.f, 0.f, 0.f);
#pragma unroll
    for (int j = 0; j < 8; ++j) {
        const float w = ((kbase + j) < len) ? 1.0f : 0.0f;
        acc.x += v[j].x * w;
        acc.y += v[j].y * w;
        acc.z += v[j].z * w;
        acc.w += v[j].w * w;
    }

    // Combine the two groups within each wave (lane ^ 32 holds same chunk).
    acc.x += __shfl_xor(acc.x, 32);
    acc.y += __shfl_xor(acc.y, 32);
    acc.z += __shfl_xor(acc.z, 32);
    acc.w += __shfl_xor(acc.w, 32);

    // Cross-wave combine within each side via 1KB LDS.
    __shared__ float4 smem[2][32];
    if (sub == 1 && (stid & 63) < 32) smem[side][lane4] = acc;
    __syncthreads();
    if (sub == 0 && stid < 32) {
        float4 o = smem[side][lane4];
        o.x += acc.x; o.y += acc.y; o.z += acc.z; o.w += acc.w;
        const float inv = (len > 0) ? (1.0f / (float)len) : 0.0f;
        o.x *= inv; o.y *= inv; o.z *= inv; o.w *= inv;
        out4[((size_t)(1 + side) * B + b) * 32 + lane4] = o;
    }
}

extern "C" void kernel_launch(void* const* d_in, const int* in_sizes, int n_in,
                              void* d_out, int out_size, void* d_ws, size_t ws_size,
                              hipStream_t stream)
{
    const float* table    = (const float*)d_in[0];
    const int*   node_idx = (const int*)d_in[1];
    const int*   pos_idx  = (const int*)d_in[2];
    const int*   pos_len  = (const int*)d_in[3];
    const int*   neg_idx  = (const int*)d_in[4];
    const int*   neg_len  = (const int*)d_in[5];
    float*       out      = (float*)d_out;

    isne_kernel<<<B, 256, 0, stream>>>(table, node_idx, pos_idx, pos_len,
                                       neg_idx, neg_len, out);
}